// Round 2
// baseline (268.453 us; speedup 1.0000x reference)
//
#include <hip/hip_runtime.h>
#include <hip/hip_bf16.h>

#define B_    4
#define N_    8192
#define TOT   (B_*N_)      // 32768 points
#define KNN_  16
#define PPW   8            // points per wave in k2
#define PITCH 80           // LDS tile pitch in halfs (160B, 16B-aligned rows)

typedef _Float16 half8  __attribute__((ext_vector_type(8)));
typedef float    floatx4 __attribute__((ext_vector_type(4)));

#define MFMA16(A, Bv, C) __builtin_amdgcn_mfma_f32_16x16x32_f16((A), (Bv), (C), 0, 0, 0)

__device__ __forceinline__ void lds_fence(){
  asm volatile("s_waitcnt lgkmcnt(0)" ::: "memory");
}
__device__ __forceinline__ half8 h8_load_f32(const float* __restrict__ p){
  float4 a = *(const float4*)p;
  float4 b = *(const float4*)(p + 4);
  half8 r;
  r[0] = (_Float16)a.x; r[1] = (_Float16)a.y; r[2] = (_Float16)a.z; r[3] = (_Float16)a.w;
  r[4] = (_Float16)b.x; r[5] = (_Float16)b.y; r[6] = (_Float16)b.z; r[7] = (_Float16)b.w;
  return r;
}
__device__ __forceinline__ void store8f(float* __restrict__ p, half8 v){
  float4 a = {(float)v[0], (float)v[1], (float)v[2], (float)v[3]};
  float4 b = {(float)v[4], (float)v[5], (float)v[6], (float)v[7]};
  *(float4*)p = a;
  *(float4*)(p + 4) = b;
}

// Fill LDS B-fragment array for a 64x64 row-major f32 weight.
// Layout: frag index (kt*4+nt)*64 + lane; lane holds W[kt*32+quad*8+j][nt*16+(lane&15)].
__device__ void fill_w64(half8* dst, const float* __restrict__ W, int tid){
  for (int i = tid; i < 512; i += 256){
    int lane = i & 63, nt = (i >> 6) & 3, kt = i >> 8;
    int n  = nt*16 + (lane & 15);
    int kb = kt*32 + ((lane >> 4) & 3)*8;
    half8 v;
    #pragma unroll
    for (int j = 0; j < 8; j++) v[j] = (_Float16)W[(kb + j)*64 + n];
    dst[i] = v;
  }
}
// d1_w is (3,64); pad K to 32 with zeros. Layout: nt*64 + lane.
__device__ void fill_d1(half8* dst, const float* __restrict__ W, int tid){
  if (tid < 256){
    int lane = tid & 63, nt = tid >> 6;
    int n  = nt*16 + (lane & 15);
    int kb = ((lane >> 4) & 3)*8;
    half8 v;
    #pragma unroll
    for (int j = 0; j < 8; j++){
      int k = kb + j;
      v[j] = (k < 3) ? (_Float16)W[k*64 + n] : (_Float16)0.0f;
    }
    dst[tid] = v;
  }
}

// ---------------- kernel 1: x = fc1(features); q/xk/xv = x @ {wq,wk,wv} ----------------
__global__ __launch_bounds__(256, 2) void k1_qkv(
    const float* __restrict__ feat, const float* __restrict__ fc1w, const float* __restrict__ fc1b,
    const float* __restrict__ wqw, const float* __restrict__ wkw, const float* __restrict__ wvw,
    _Float16* __restrict__ qws, _Float16* __restrict__ kws, _Float16* __restrict__ vws)
{
  __shared__ half8 Sfc1[512], Sq[512], Sk[512], Sv[512];
  __shared__ alignas(16) _Float16 xt[4][16*PITCH];
  const int tid = threadIdx.x;
  fill_w64(Sfc1, fc1w, tid);
  fill_w64(Sq, wqw, tid);
  fill_w64(Sk, wkw, tid);
  fill_w64(Sv, wvw, tid);
  __syncthreads();

  const int wave = tid >> 6, lane = tid & 63, quad = lane >> 4, m16 = lane & 15;
  _Float16* tx = &xt[wave][0];
  const int rowbase = blockIdx.x*64 + wave*16;
  float fb[4];
  #pragma unroll
  for (int nt = 0; nt < 4; nt++) fb[nt] = fc1b[nt*16 + m16];

  const int arow = rowbase + m16;
  half8 Fa0 = h8_load_f32(&feat[arow*64 + quad*8]);
  half8 Fa1 = h8_load_f32(&feat[arow*64 + 32 + quad*8]);
  const floatx4 z4 = {0.f, 0.f, 0.f, 0.f};

  #pragma unroll
  for (int nt = 0; nt < 4; nt++){
    floatx4 acc = MFMA16(Fa0, Sfc1[nt*64 + lane], z4);
    acc = MFMA16(Fa1, Sfc1[(4 + nt)*64 + lane], acc);
    const int col = nt*16 + m16;
    #pragma unroll
    for (int r = 0; r < 4; r++)
      tx[(quad*4 + r)*PITCH + col] = (_Float16)(acc[r] + fb[nt]);
  }
  lds_fence();
  const half8 Ax0 = *(const half8*)&tx[m16*PITCH + quad*8];
  const half8 Ax1 = *(const half8*)&tx[m16*PITCH + 32 + quad*8];

#define EMIT_QKV(S, OUT)                                                      \
  { _Pragma("unroll")                                                         \
    for (int nt = 0; nt < 4; nt++){                                           \
      floatx4 acc = MFMA16(Ax0, S[nt*64 + lane], z4);                         \
      acc = MFMA16(Ax1, S[(4 + nt)*64 + lane], acc);                          \
      _Pragma("unroll")                                                       \
      for (int r = 0; r < 4; r++)                                             \
        OUT[(rowbase + quad*4 + r)*64 + nt*16 + m16] = (_Float16)acc[r];      \
    } }
  EMIT_QKV(Sq, qws)
  EMIT_QKV(Sk, kws)
  EMIT_QKV(Sv, vws)
#undef EMIT_QKV
}

// ---------------- kernel 2: per-point fused pos_enc / attention ----------------
__global__ __launch_bounds__(256, 2) void k2_point(
    const float* __restrict__ xyz, const int* __restrict__ knn,
    const float* __restrict__ d1w, const float* __restrict__ d1b,
    const float* __restrict__ d2w, const float* __restrict__ d2b,
    const float* __restrict__ g1w, const float* __restrict__ g1b,
    const float* __restrict__ g2w, const float* __restrict__ g2b,
    const _Float16* __restrict__ qws, const _Float16* __restrict__ kws,
    const _Float16* __restrict__ vws,
    _Float16* __restrict__ r0, float* __restrict__ attn_out)
{
  __shared__ half8 Sd1[256], Sd2[512], Sg1[512], Sg2[512];
  __shared__ alignas(16) _Float16 tiles[4][2][16*PITCH];
  const int tid = threadIdx.x;
  fill_d1(Sd1, d1w, tid);
  fill_w64(Sd2, d2w, tid);
  fill_w64(Sg1, g1w, tid);
  fill_w64(Sg2, g2w, tid);
  __syncthreads();

  const int wave = tid >> 6, lane = tid & 63, quad = lane >> 4, m16 = lane & 15;
  _Float16* tA = &tiles[wave][0][0];
  _Float16* tB = &tiles[wave][1][0];

  // weight fragments live in registers across the point loop (no LDS reads per MFMA)
  half8 Fd1[4], Fd2[2][4], Fg1[2][4], Fg2[2][4];
  #pragma unroll
  for (int nt = 0; nt < 4; nt++){
    Fd1[nt] = Sd1[nt*64 + lane];
    #pragma unroll
    for (int kt = 0; kt < 2; kt++){
      Fd2[kt][nt] = Sd2[(kt*4 + nt)*64 + lane];
      Fg1[kt][nt] = Sg1[(kt*4 + nt)*64 + lane];
      Fg2[kt][nt] = Sg2[(kt*4 + nt)*64 + lane];
    }
  }
  float bd1[4], bd2[4], bg1[4], bg2[4];
  #pragma unroll
  for (int nt = 0; nt < 4; nt++){
    const int c = nt*16 + m16;
    bd1[nt] = d1b[c]; bd2[nt] = d2b[c];
    bg1[nt] = g1b[c]; bg2[nt] = g2b[c];
  }
  const floatx4 z4 = {0.f, 0.f, 0.f, 0.f};

  for (int p = 0; p < PPW; p++){
    const int gpt  = blockIdx.x*(4*PPW) + wave*PPW + p;   // global point id = b*N+n
    const int b    = gpt >> 13;                           // N=8192
    const int idxm = knn[gpt*KNN_ + m16];                 // neighbor of row m16
    const int grow = b*N_ + idxm;

    // relative position (only quad 0, k<3 is nonzero)
    half8 Ar;
    #pragma unroll
    for (int j = 0; j < 8; j++) Ar[j] = (_Float16)0.0f;
    if (quad == 0){
      #pragma unroll
      for (int j = 0; j < 3; j++)
        Ar[j] = (_Float16)(xyz[gpt*3 + j] - xyz[grow*3 + j]);
    }

    // stage 1: t = relu(rel @ d1 + b)  -> tA
    #pragma unroll
    for (int nt = 0; nt < 4; nt++){
      floatx4 acc = MFMA16(Ar, Fd1[nt], z4);
      const int col = nt*16 + m16;
      #pragma unroll
      for (int r = 0; r < 4; r++){
        float t = acc[r] + bd1[nt];
        tA[(quad*4 + r)*PITCH + col] = (_Float16)(t > 0.f ? t : 0.f);
      }
    }
    lds_fence();
    const half8 At0 = *(const half8*)&tA[m16*PITCH + quad*8];
    const half8 At1 = *(const half8*)&tA[m16*PITCH + 32 + quad*8];

    // stage 2: P = t @ d2 + b  -> tB
    #pragma unroll
    for (int nt = 0; nt < 4; nt++){
      floatx4 acc = MFMA16(At0, Fd2[0][nt], z4);
      acc = MFMA16(At1, Fd2[1][nt], acc);
      const int col = nt*16 + m16;
      #pragma unroll
      for (int r = 0; r < 4; r++)
        tB[(quad*4 + r)*PITCH + col] = (_Float16)(acc[r] + bd2[nt]);
    }
    lds_fence();
    const half8 Pa0 = *(const half8*)&tB[m16*PITCH + quad*8];
    const half8 Pa1 = *(const half8*)&tB[m16*PITCH + 32 + quad*8];

    // gather K, broadcast q; H = q - k + P
    const half8 Ka0 = *(const half8*)&kws[grow*64 + quad*8];
    const half8 Ka1 = *(const half8*)&kws[grow*64 + 32 + quad*8];
    const half8 Qa0 = *(const half8*)&qws[gpt*64 + quad*8];
    const half8 Qa1 = *(const half8*)&qws[gpt*64 + 32 + quad*8];
    const half8 H0 = Qa0 - Ka0 + Pa0;
    const half8 H1 = Qa1 - Ka1 + Pa1;

    // stage 3: u = relu(H @ g1 + b)  -> tA
    #pragma unroll
    for (int nt = 0; nt < 4; nt++){
      floatx4 acc = MFMA16(H0, Fg1[0][nt], z4);
      acc = MFMA16(H1, Fg1[1][nt], acc);
      const int col = nt*16 + m16;
      #pragma unroll
      for (int r = 0; r < 4; r++){
        float t = acc[r] + bg1[nt];
        tA[(quad*4 + r)*PITCH + col] = (_Float16)(t > 0.f ? t : 0.f);
      }
    }
    lds_fence();
    const half8 U0 = *(const half8*)&tA[m16*PITCH + quad*8];
    const half8 U1 = *(const half8*)&tA[m16*PITCH + 32 + quad*8];

    // stage 4: logits = u @ g2 + b   (C layout)
    float A2[4][4];
    #pragma unroll
    for (int nt = 0; nt < 4; nt++){
      floatx4 acc = MFMA16(U0, Fg2[0][nt], z4);
      acc = MFMA16(U1, Fg2[1][nt], acc);
      #pragma unroll
      for (int r = 0; r < 4; r++) A2[nt][r] = acc[r] + bg2[nt];
    }

    // softmax over the 16 neighbors (rows): local 4 + cross-quad shfl_xor(16,32)
    #pragma unroll
    for (int nt = 0; nt < 4; nt++){
      float mx = fmaxf(fmaxf(A2[nt][0], A2[nt][1]), fmaxf(A2[nt][2], A2[nt][3]));
      mx = fmaxf(mx, __shfl_xor(mx, 16));
      mx = fmaxf(mx, __shfl_xor(mx, 32));
      float s = 0.f;
      #pragma unroll
      for (int r = 0; r < 4; r++){
        float e = expf((A2[nt][r] - mx)*0.125f);   // logits / sqrt(64)
        A2[nt][r] = e; s += e;
      }
      s += __shfl_xor(s, 16);
      s += __shfl_xor(s, 32);
      const float inv = 1.0f / s;
      const int col = nt*16 + m16;
      #pragma unroll
      for (int r = 0; r < 4; r++)
        tA[(quad*4 + r)*PITCH + col] = (_Float16)(A2[nt][r]*inv);
    }
    lds_fence();
    const half8 Aa0 = *(const half8*)&tA[m16*PITCH + quad*8];
    const half8 Aa1 = *(const half8*)&tA[m16*PITCH + 32 + quad*8];
    const half8 Va0 = *(const half8*)&vws[grow*64 + quad*8];
    const half8 Va1 = *(const half8*)&vws[grow*64 + 32 + quad*8];

    // attn output (f32), A-layout contiguous 32B stores per half
    float* ap = attn_out + ((size_t)gpt*KNN_ + m16)*64;
    store8f(ap + quad*8, Aa0);
    store8f(ap + 32 + quad*8, Aa1);

    // res0 = sum_k attn * (v + pos_enc); reduce over the 16 m-lanes in each quad
    float w0[8], w1[8];
    #pragma unroll
    for (int j = 0; j < 8; j++){
      w0[j] = (float)Aa0[j] * ((float)Va0[j] + (float)Pa0[j]);
      w1[j] = (float)Aa1[j] * ((float)Va1[j] + (float)Pa1[j]);
    }
    #pragma unroll
    for (int mask = 1; mask < 16; mask <<= 1){
      #pragma unroll
      for (int j = 0; j < 8; j++){
        w0[j] += __shfl_xor(w0[j], mask);
        w1[j] += __shfl_xor(w1[j], mask);
      }
    }
    if (m16 == 0){
      half8 o0, o1;
      #pragma unroll
      for (int j = 0; j < 8; j++){ o0[j] = (_Float16)w0[j]; o1[j] = (_Float16)w1[j]; }
      *(half8*)&r0[gpt*64 + quad*8] = o0;
      *(half8*)&r0[gpt*64 + 32 + quad*8] = o1;
    }
  }
}

// ---------------- kernel 3: res = res0 @ fc2 + fc2_b + features ----------------
__global__ __launch_bounds__(256, 2) void k3_fc2(
    const _Float16* __restrict__ r0, const float* __restrict__ fc2w,
    const float* __restrict__ fc2b, const float* __restrict__ feat,
    float* __restrict__ out_res)
{
  __shared__ half8 S[512];
  const int tid = threadIdx.x;
  fill_w64(S, fc2w, tid);
  __syncthreads();

  const int wave = tid >> 6, lane = tid & 63, quad = lane >> 4, m16 = lane & 15;
  const int rowbase = blockIdx.x*64 + wave*16;
  float fb[4];
  #pragma unroll
  for (int nt = 0; nt < 4; nt++) fb[nt] = fc2b[nt*16 + m16];

  const half8 A0 = *(const half8*)&r0[(rowbase + m16)*64 + quad*8];
  const half8 A1 = *(const half8*)&r0[(rowbase + m16)*64 + 32 + quad*8];
  const floatx4 z4 = {0.f, 0.f, 0.f, 0.f};

  #pragma unroll
  for (int nt = 0; nt < 4; nt++){
    floatx4 acc = MFMA16(A0, S[nt*64 + lane], z4);
    acc = MFMA16(A1, S[(4 + nt)*64 + lane], acc);
    #pragma unroll
    for (int r = 0; r < 4; r++){
      const int rowg = rowbase + quad*4 + r;
      const int col  = nt*16 + m16;
      out_res[rowg*64 + col] = acc[r] + fb[nt] + feat[rowg*64 + col];
    }
  }
}

extern "C" void kernel_launch(void* const* d_in, const int* in_sizes, int n_in,
                              void* d_out, int out_size, void* d_ws, size_t ws_size,
                              hipStream_t stream)
{
  (void)in_sizes; (void)n_in; (void)out_size; (void)ws_size;
  const float* xyz  = (const float*)d_in[0];
  const float* feat = (const float*)d_in[1];
  const int*   knn  = (const int*)d_in[2];
  const float* fc1w = (const float*)d_in[3];
  const float* fc1b = (const float*)d_in[4];
  const float* fc2w = (const float*)d_in[5];
  const float* fc2b = (const float*)d_in[6];
  const float* d1w  = (const float*)d_in[7];
  const float* d1b  = (const float*)d_in[8];
  const float* d2w  = (const float*)d_in[9];
  const float* d2b  = (const float*)d_in[10];
  const float* g1w  = (const float*)d_in[11];
  const float* g1b  = (const float*)d_in[12];
  const float* g2w  = (const float*)d_in[13];
  const float* g2b  = (const float*)d_in[14];
  const float* wq   = (const float*)d_in[15];
  const float* wk   = (const float*)d_in[16];
  const float* wv   = (const float*)d_in[17];

  _Float16* ws  = (_Float16*)d_ws;
  _Float16* qws = ws;                      // TOT*64 halfs
  _Float16* kws = ws + (size_t)TOT*64;
  _Float16* vws = ws + (size_t)2*TOT*64;
  _Float16* r0  = ws + (size_t)3*TOT*64;

  float* out      = (float*)d_out;
  float* out_res  = out;                     // (B,N,64)
  float* out_attn = out + (size_t)TOT*64;    // (B,N,K,64)

  k1_qkv<<<TOT/64, 256, 0, stream>>>(feat, fc1w, fc1b, wq, wk, wv, qws, kws, vws);
  k2_point<<<TOT/(4*PPW), 256, 0, stream>>>(xyz, knn, d1w, d1b, d2w, d2b,
                                            g1w, g1b, g2w, g2b,
                                            qws, kws, vws, r0, out_attn);
  k3_fc2<<<TOT/64, 256, 0, stream>>>(r0, fc2w, fc2b, feat, out_res);
}